// Round 1
// baseline (653.084 us; speedup 1.0000x reference)
//
#include <hip/hip_runtime.h>

#define BB 2
#define NN 1024
#define MM 1024
#define SS 4
#define DMODEL 512
#define HH 8
#define CC 64
// scale = 1/sqrt(64) = 0.125

// ---------------------------------------------------------------------------
// Kernel 1: projections  y = x @ W^T + bias, written in (b,h,n,c) layout.
// x: (B*1024, 512) row-major; W: (512,512) row-major (torch Linear weight).
// 64x64 output tile per block, 4x4 register micro-tile, k-tile 16.
// ---------------------------------------------------------------------------
__global__ __launch_bounds__(256) void proj_kernel(
    const float* __restrict__ xq, const float* __restrict__ xk, const float* __restrict__ xv,
    const float* __restrict__ Wq, const float* __restrict__ Wk, const float* __restrict__ Wv,
    const float* __restrict__ bq, const float* __restrict__ bk, const float* __restrict__ bv,
    float* __restrict__ wsbase)
{
    __shared__ __align__(16) float xs[16 * 68];   // [kk][row], +4 pad rowstride for banks
    __shared__ __align__(16) float wsm[16 * 68];  // [kk][col]

    const int z = blockIdx.z;
    const float* x    = (z == 0) ? xq : (z == 1) ? xk : xv;
    const float* W    = (z == 0) ? Wq : (z == 1) ? Wk : Wv;
    const float* bias = (z == 0) ? bq : (z == 1) ? bk : bv;
    float* out = wsbase + (size_t)z * (BB * HH * NN * CC);

    const int t   = threadIdx.x;
    const int tx  = t & 15, ty = t >> 4;
    const int r0  = blockIdx.y * 64;   // output row tile (b*1024+n)
    const int o0  = blockIdx.x * 64;   // output col tile (= h*64)
    const int kkq = t & 15;            // k index within k-tile
    const int rr  = t >> 4;            // base row within 64-tile

    float4 acc[4];  // acc[ii] over jj
    #pragma unroll
    for (int i = 0; i < 4; ++i) { acc[i].x = 0.f; acc[i].y = 0.f; acc[i].z = 0.f; acc[i].w = 0.f; }

    #pragma unroll 1
    for (int kt = 0; kt < 32; ++kt) {
        const int k0 = kt * 16;
        __syncthreads();
        #pragma unroll
        for (int i = 0; i < 4; ++i) {
            const int row = rr + i * 16;
            xs[kkq * 68 + row]  = x[(size_t)(r0 + row) * DMODEL + k0 + kkq];
            wsm[kkq * 68 + row] = W[(size_t)(o0 + row) * DMODEL + k0 + kkq];
        }
        __syncthreads();
        #pragma unroll
        for (int kk = 0; kk < 16; ++kk) {
            const float4 a  = *(const float4*)&xs[kk * 68 + ty * 4];   // broadcast over tx
            const float4 w4 = *(const float4*)&wsm[kk * 68 + tx * 4];
            acc[0].x += a.x * w4.x; acc[0].y += a.x * w4.y; acc[0].z += a.x * w4.z; acc[0].w += a.x * w4.w;
            acc[1].x += a.y * w4.x; acc[1].y += a.y * w4.y; acc[1].z += a.y * w4.z; acc[1].w += a.y * w4.w;
            acc[2].x += a.z * w4.x; acc[2].y += a.z * w4.y; acc[2].z += a.z * w4.z; acc[2].w += a.z * w4.w;
            acc[3].x += a.w * w4.x; acc[3].y += a.w * w4.y; acc[3].z += a.w * w4.z; acc[3].w += a.w * w4.w;
        }
    }

    const float4 bv4 = *(const float4*)&bias[o0 + tx * 4];
    const int h = o0 >> 6;
    #pragma unroll
    for (int ii = 0; ii < 4; ++ii) {
        const int r = r0 + ty * 4 + ii;
        const int b = r >> 10, n = r & 1023;
        float4 o;
        o.x = acc[ii].x + bv4.x; o.y = acc[ii].y + bv4.y;
        o.z = acc[ii].z + bv4.z; o.w = acc[ii].w + bv4.w;
        *(float4*)&out[((size_t)(b * HH + h) * NN + n) * CC + tx * 4] = o;
    }
}

// ---------------------------------------------------------------------------
// Kernel 2: fused subspace attention. One block per (b,h, 8-row n-tile).
// Phase B: S[8][1024] = q @ k^T via 32-m LDS tiles, 8-way c-split + reduce.
// Phase C: per-s softmax denominators (no max-sub; logits bounded).
// Phase D: exp+normalize -> attn global write + attn@V accumulate.
// ---------------------------------------------------------------------------
__global__ __launch_bounds__(256) void attn_kernel(
    const float* __restrict__ qws, const float* __restrict__ kws, const float* __restrict__ vws,
    const float* __restrict__ qsub, const float* __restrict__ ksub,
    float* __restrict__ out_hidden, float* __restrict__ out_attn)
{
    // 52,096 B of LDS, manually carved (all offsets 16B-aligned)
    __shared__ __align__(16) float smem[13024];
    float* s_S   = smem;                        // [8][1024]     8192 floats
    float* s_kv  = smem + 8192;                 // [32][68]      2176 floats (k/v staging)
    float* s_q   = smem + 8192 + 2176;          // [8][68]        544 floats
    float* s_u   = smem + 8192 + 2176 + 544;    // union: red[8][256] / attn[4][8][32]  2048 floats
    float* s_inv = s_u + 2048;                  // [4][8]
    float* s_qs  = s_inv + 32;                  // [4][8]

    const int t     = threadIdx.x;
    const int blk   = blockIdx.x;       // 0..2047
    const int ntile = blk & 127;
    const int bh    = blk >> 7;         // b*8+h
    const int b     = bh >> 3;
    const int h     = bh & 7;
    const int n0    = ntile * 8;

    // ---- Phase A: load q tile + qs scales ----
    const float* qbase = qws + ((size_t)bh * NN + n0) * CC;
    for (int i = t; i < 8 * CC; i += 256) {
        const int n = i >> 6, c = i & 63;
        s_q[n * 68 + c] = qbase[n * CC + c];
    }
    if (t < 32) {
        const int s = t >> 3, n = t & 7;
        s_qs[s * 8 + n] = qsub[((size_t)b * SS + s) * NN + n0 + n] * 0.125f;
    }

    // ---- Phase B: S = q @ k^T ----
    const float* kb = kws + (size_t)bh * MM * CC;
    #pragma unroll 1
    for (int mt = 0; mt < 32; ++mt) {
        __syncthreads();
        {   // stage 32x64 k tile
            const float4* src = (const float4*)(kb + (size_t)mt * 32 * CC);
            #pragma unroll
            for (int i = 0; i < 2; ++i) {
                const int f = t * 2 + i;           // 0..511 float4s
                const int row = f >> 4, c4 = f & 15;
                *(float4*)&s_kv[row * 68 + c4 * 4] = src[row * 16 + c4];
            }
        }
        __syncthreads();
        {   // partial dots: thread covers m=t&31, all 8 n, c-slice dup=t>>5
            const int m = t & 31, dup = t >> 5;
            float part[8];
            #pragma unroll
            for (int n = 0; n < 8; ++n) part[n] = 0.f;
            #pragma unroll
            for (int jj = 0; jj < 2; ++jj) {
                const int j = dup * 2 + jj;        // float4 chunk 0..15
                const float4 k4 = *(const float4*)&s_kv[m * 68 + j * 4];
                #pragma unroll
                for (int n = 0; n < 8; ++n) {
                    const float4 q4 = *(const float4*)&s_q[n * 68 + j * 4];
                    part[n] += q4.x * k4.x + q4.y * k4.y + q4.z * k4.z + q4.w * k4.w;
                }
            }
            #pragma unroll
            for (int n = 0; n < 8; ++n) s_u[n * 256 + m * 8 + dup] = part[n];
        }
        __syncthreads();
        {   // reduce 8 c-slices
            const int n = t >> 5, m = t & 31;
            const float4* r = (const float4*)&s_u[n * 256 + m * 8];
            const float4 a = r[0], c = r[1];
            s_S[n * 1024 + mt * 32 + m] =
                ((a.x + a.y) + (a.z + a.w)) + ((c.x + c.y) + (c.z + c.w));
        }
    }
    __syncthreads();

    // ---- Phase C: softmax denominators per s ----
    {
        const int n = t >> 5, ml = t & 31;
        const float* Srow = &s_S[n * 1024];
        #pragma unroll
        for (int s = 0; s < SS; ++s) {
            const float* ksr = ksub + ((size_t)b * SS + s) * MM;
            const float qsn = s_qs[s * 8 + n];
            float acc = 0.f;
            #pragma unroll 4
            for (int j = 0; j < 32; ++j) {
                const int m = j * 32 + ml;
                acc += __expf(Srow[m] * qsn * ksr[m]);
            }
            #pragma unroll
            for (int off = 16; off > 0; off >>= 1) acc += __shfl_xor(acc, off);
            if (ml == 0) s_inv[s * 8 + n] = 1.0f / acc;
        }
    }
    __syncthreads();

    // ---- Phase D: attn write + attn @ V ----
    const float* vb = vws + (size_t)bh * MM * CC;
    const int cq = t & 15, g = t >> 4;
    const int sA = g & 3, half = (g >> 2) & 1, mmg = g >> 3;
    float4 accs[4];
    #pragma unroll
    for (int i = 0; i < 4; ++i) { accs[i].x = 0.f; accs[i].y = 0.f; accs[i].z = 0.f; accs[i].w = 0.f; }

    const int nA = t >> 5, mlA = t & 31;   // attn-pass mapping
    const float SqsA[4] = { s_qs[0 * 8 + nA], s_qs[1 * 8 + nA], s_qs[2 * 8 + nA], s_qs[3 * 8 + nA] };

    #pragma unroll 1
    for (int mt = 0; mt < 32; ++mt) {
        __syncthreads();
        {   // stage 32x64 v tile
            const float4* src = (const float4*)(vb + (size_t)mt * 32 * CC);
            #pragma unroll
            for (int i = 0; i < 2; ++i) {
                const int f = t * 2 + i;
                const int row = f >> 4, c4 = f & 15;
                *(float4*)&s_kv[row * 68 + c4 * 4] = src[row * 16 + c4];
            }
        }
        __syncthreads();
        {   // exp + normalize + global store + stash in LDS
            const int m = mt * 32 + mlA;
            const float Sv = s_S[nA * 1024 + m];
            #pragma unroll
            for (int s = 0; s < SS; ++s) {
                const float ksv = ksub[((size_t)b * SS + s) * MM + m];
                const float e = __expf(Sv * SqsA[s] * ksv) * s_inv[s * 8 + nA];
                out_attn[(((size_t)(bh * SS + s)) * NN + (n0 + nA)) * MM + m] = e;
                s_u[(s * 8 + nA) * 32 + mlA] = e;   // note: written 4x, last s kept per slot? no:
                // each s has its own slot: index includes s -> distinct. (kept for clarity)
            }
        }
        __syncthreads();
        {   // AV micro-tile: 4 c x 4 n for (sA, half), m-range mmg*16..+15
            #pragma unroll
            for (int mml = 0; mml < 16; ++mml) {
                const int mm = mmg * 16 + mml;
                const float4 v4 = *(const float4*)&s_kv[mm * 68 + cq * 4];
                #pragma unroll
                for (int nn = 0; nn < 4; ++nn) {
                    const float a = s_u[(sA * 8 + half * 4 + nn) * 32 + mm];
                    accs[nn].x += a * v4.x; accs[nn].y += a * v4.y;
                    accs[nn].z += a * v4.z; accs[nn].w += a * v4.w;
                }
            }
        }
    }

    // ---- final: reduce the two mm-groups, write hidden ----
    __syncthreads();
    if (mmg == 1) {
        #pragma unroll
        for (int nn = 0; nn < 4; ++nn)
            *(float4*)&s_u[(sA * 8 + half * 4 + nn) * 64 + cq * 4] = accs[nn];
    }
    __syncthreads();
    if (mmg == 0) {
        #pragma unroll
        for (int nn = 0; nn < 4; ++nn) {
            const float4 o2 = *(const float4*)&s_u[(sA * 8 + half * 4 + nn) * 64 + cq * 4];
            float4 o;
            o.x = accs[nn].x + o2.x; o.y = accs[nn].y + o2.y;
            o.z = accs[nn].z + o2.z; o.w = accs[nn].w + o2.w;
            const int n = half * 4 + nn;
            *(float4*)&out_hidden[(((size_t)b * SS + sA) * NN + (n0 + n)) * DMODEL + h * CC + cq * 4] = o;
        }
    }
}

extern "C" void kernel_launch(void* const* d_in, const int* in_sizes, int n_in,
                              void* d_out, int out_size, void* d_ws, size_t ws_size,
                              hipStream_t stream) {
    const float* xq   = (const float*)d_in[0];
    const float* xk   = (const float*)d_in[1];
    const float* xv   = (const float*)d_in[2];
    const float* qsub = (const float*)d_in[3];
    const float* ksub = (const float*)d_in[4];
    const float* Wq   = (const float*)d_in[5];
    const float* bq   = (const float*)d_in[6];
    const float* Wk   = (const float*)d_in[7];
    const float* bk   = (const float*)d_in[8];
    const float* Wv   = (const float*)d_in[9];
    const float* bv   = (const float*)d_in[10];

    float* ws = (float*)d_ws;                       // needs 12.58 MB: q,k,v in (b,h,n,c)
    const size_t one = (size_t)BB * HH * NN * CC;   // 1,048,576 floats each
    float* out_hidden = (float*)d_out;              // (B,S,N,512)
    float* out_attn   = out_hidden + (size_t)BB * SS * NN * DMODEL;  // (B,H,S,N,M)

    proj_kernel<<<dim3(8, 32, 3), 256, 0, stream>>>(xq, xk, xv, Wq, Wk, Wv, bq, bk, bv, ws);
    attn_kernel<<<dim3(2048), 256, 0, stream>>>(ws, ws + one, ws + 2 * one,
                                                qsub, ksub, out_hidden, out_attn);
}

// Round 2
// 468.319 us; speedup vs baseline: 1.3945x; 1.3945x over previous
//
#include <hip/hip_runtime.h>

#define BB 2
#define NN 1024
#define MM 1024
#define SS 4
#define DMODEL 512
#define HH 8
#define CC 64
// scale = 1/sqrt(64) = 0.125

typedef __attribute__((ext_vector_type(8))) short short8;
typedef __attribute__((ext_vector_type(4))) short short4v;
typedef __attribute__((ext_vector_type(2))) short short2v;
typedef __attribute__((ext_vector_type(4))) float f32x4;

__device__ __forceinline__ unsigned short f2bf(float x) {   // truncation (lo-part captures residual)
    union { float f; unsigned u; } c; c.f = x;
    return (unsigned short)(c.u >> 16);
}
__device__ __forceinline__ float bf2f(unsigned short h) {
    union { float f; unsigned u; } c; c.u = ((unsigned)h) << 16;
    return c.f;
}

// ---------------------------------------------------------------------------
// Kernel 1: projections  y = x @ W^T + bias, written in (b,h,n,c) layout.
// (unchanged from R1 — ~25 µs by cycle model; profile will confirm)
// ---------------------------------------------------------------------------
__global__ __launch_bounds__(256) void proj_kernel(
    const float* __restrict__ xq, const float* __restrict__ xk, const float* __restrict__ xv,
    const float* __restrict__ Wq, const float* __restrict__ Wk, const float* __restrict__ Wv,
    const float* __restrict__ bq, const float* __restrict__ bk, const float* __restrict__ bv,
    float* __restrict__ wsbase)
{
    __shared__ __align__(16) float xs[16 * 68];
    __shared__ __align__(16) float wsm[16 * 68];

    const int z = blockIdx.z;
    const float* x    = (z == 0) ? xq : (z == 1) ? xk : xv;
    const float* W    = (z == 0) ? Wq : (z == 1) ? Wk : Wv;
    const float* bias = (z == 0) ? bq : (z == 1) ? bk : bv;
    float* out = wsbase + (size_t)z * (BB * HH * NN * CC);

    const int t   = threadIdx.x;
    const int tx  = t & 15, ty = t >> 4;
    const int r0  = blockIdx.y * 64;
    const int o0  = blockIdx.x * 64;
    const int kkq = t & 15;
    const int rr  = t >> 4;

    float4 acc[4];
    #pragma unroll
    for (int i = 0; i < 4; ++i) { acc[i].x = 0.f; acc[i].y = 0.f; acc[i].z = 0.f; acc[i].w = 0.f; }

    #pragma unroll 1
    for (int kt = 0; kt < 32; ++kt) {
        const int k0 = kt * 16;
        __syncthreads();
        #pragma unroll
        for (int i = 0; i < 4; ++i) {
            const int row = rr + i * 16;
            xs[kkq * 68 + row]  = x[(size_t)(r0 + row) * DMODEL + k0 + kkq];
            wsm[kkq * 68 + row] = W[(size_t)(o0 + row) * DMODEL + k0 + kkq];
        }
        __syncthreads();
        #pragma unroll
        for (int kk = 0; kk < 16; ++kk) {
            const float4 a  = *(const float4*)&xs[kk * 68 + ty * 4];
            const float4 w4 = *(const float4*)&wsm[kk * 68 + tx * 4];
            acc[0].x += a.x * w4.x; acc[0].y += a.x * w4.y; acc[0].z += a.x * w4.z; acc[0].w += a.x * w4.w;
            acc[1].x += a.y * w4.x; acc[1].y += a.y * w4.y; acc[1].z += a.y * w4.z; acc[1].w += a.y * w4.w;
            acc[2].x += a.z * w4.x; acc[2].y += a.z * w4.y; acc[2].z += a.z * w4.z; acc[2].w += a.z * w4.w;
            acc[3].x += a.w * w4.x; acc[3].y += a.w * w4.y; acc[3].z += a.w * w4.z; acc[3].w += a.w * w4.w;
        }
    }

    const float4 bv4 = *(const float4*)&bias[o0 + tx * 4];
    const int h = o0 >> 6;
    #pragma unroll
    for (int ii = 0; ii < 4; ++ii) {
        const int r = r0 + ty * 4 + ii;
        const int b = r >> 10, n = r & 1023;
        float4 o;
        o.x = acc[ii].x + bv4.x; o.y = acc[ii].y + bv4.y;
        o.z = acc[ii].z + bv4.z; o.w = acc[ii].w + bv4.w;
        *(float4*)&out[((size_t)(b * HH + h) * NN + n) * CC + tx * 4] = o;
    }
}

// ---------------------------------------------------------------------------
// Kernel 2: fused subspace attention, MFMA bf16.
// Block = (b,h, 8-row n-tile). Phase B: S = q@k^T via split-bf16 (hi/lo) MFMA,
// S kept fp32 in LDS; softmax denominators accumulated in-register from MFMA
// output. Phase C: exp+normalize -> attn global write (fp32) + bf16 stash,
// then attn@V via single-bf16 MFMA.
// ---------------------------------------------------------------------------
__global__ __launch_bounds__(256) void attn_kernel(
    const float* __restrict__ qws, const float* __restrict__ kws, const float* __restrict__ vws,
    const float* __restrict__ qsub, const float* __restrict__ ksub,
    float* __restrict__ out_hidden, float* __restrict__ out_attn)
{
    __shared__ __align__(16) float s_S[8 * 1036];           // S fp32, row stride 1036 (16B-aligned, ~2-way banks)
    __shared__ __align__(16) unsigned short s_kb[9216];     // B: kh[64][72] + kl[64][72]; C: vT[64][72] + stash[32][72]
    __shared__ __align__(16) unsigned short s_qh[16 * 72];  // q hi, rows 8..15 zeroed (MFMA M=16 pad)
    __shared__ __align__(16) unsigned short s_ql[16 * 72];  // q lo
    __shared__ float s_qs[32];                              // qsub * 0.125, [s][n]
    __shared__ float s_inv[32];                             // 1/denom, [s][n]
    __shared__ float s_red[128];                            // cross-wave denom reduce [w][n][s]

    unsigned short* s_kh = s_kb;
    unsigned short* s_kl = s_kb + 64 * 72;
    unsigned short* s_vT = s_kb;            // phase C alias of kh
    unsigned short* s_at = s_kb + 64 * 72;  // phase C alias of kl: attn stash [32 sn][72]

    const int t     = threadIdx.x;
    const int blk   = blockIdx.x;           // 2048 = (bh)*128 + ntile
    const int ntile = blk & 127;
    const int bh    = blk >> 7;
    const int b     = bh >> 3;
    const int h     = bh & 7;
    const int n0    = ntile * 8;

    const int lane = t & 63;
    const int w    = t >> 6;                // wave 0..3
    const int l15  = lane & 15;
    const int quad = lane >> 4;

    // ---- Phase A: q tile -> split bf16 LDS; qs scales ----
    if (t < 128) {
        const int row = t >> 4, c4 = t & 15;
        const float4 qv = *(const float4*)&qws[((size_t)bh * NN + n0 + row) * CC + c4 * 4];
        const unsigned short h0 = f2bf(qv.x), h1 = f2bf(qv.y), h2 = f2bf(qv.z), h3 = f2bf(qv.w);
        short4v hh = { (short)h0, (short)h1, (short)h2, (short)h3 };
        short4v ll = { (short)f2bf(qv.x - bf2f(h0)), (short)f2bf(qv.y - bf2f(h1)),
                       (short)f2bf(qv.z - bf2f(h2)), (short)f2bf(qv.w - bf2f(h3)) };
        *(short4v*)&s_qh[row * 72 + c4 * 4] = hh;
        *(short4v*)&s_ql[row * 72 + c4 * 4] = ll;
    }
    for (int i = 576 + t; i < 1152; i += 256) { s_qh[i] = 0; s_ql[i] = 0; }   // zero pad rows 8..15
    if (t < 32) s_qs[t] = qsub[((size_t)b * SS + (t >> 3)) * NN + n0 + (t & 7)] * 0.125f;
    __syncthreads();

    // per-wave q fragments (A-layout: row = lane&15, k = quad*8+j), reused all m-tiles
    const short8 qh0 = *(const short8*)&s_qh[l15 * 72 + 0  + quad * 8];
    const short8 qh1 = *(const short8*)&s_qh[l15 * 72 + 32 + quad * 8];
    const short8 ql0 = *(const short8*)&s_ql[l15 * 72 + 0  + quad * 8];
    const short8 ql1 = *(const short8*)&s_ql[l15 * 72 + 32 + quad * 8];

    // denom accumulators + qs registers (valid for quads 0,1 -> rows 0..7)
    float dn[4][4];
    #pragma unroll
    for (int s = 0; s < 4; ++s)
        #pragma unroll
        for (int r = 0; r < 4; ++r) dn[s][r] = 0.f;
    float qsr[4][4];
    {
        const int nq = (quad & 1) * 4;
        #pragma unroll
        for (int s = 0; s < 4; ++s)
            #pragma unroll
            for (int r = 0; r < 4; ++r) qsr[s][r] = s_qs[s * 8 + nq + r];
    }

    // ---- Phase B: S = q@k^T (split bf16), S->LDS fp32, denoms in-register ----
    const float* kg = kws + (size_t)bh * MM * CC;
    #pragma unroll 1
    for (int mt = 0; mt < 16; ++mt) {
        const int m0 = mt * 64;
        #pragma unroll
        for (int i = 0; i < 4; ++i) {               // stage 64x64 fp32 -> kh/kl bf16
            const int f = t + i * 256;
            const int row = f >> 4, c4 = f & 15;
            const float4 kv = *(const float4*)&kg[(size_t)(m0 + row) * CC + c4 * 4];
            const unsigned short h0 = f2bf(kv.x), h1 = f2bf(kv.y), h2 = f2bf(kv.z), h3 = f2bf(kv.w);
            short4v hh = { (short)h0, (short)h1, (short)h2, (short)h3 };
            short4v ll = { (short)f2bf(kv.x - bf2f(h0)), (short)f2bf(kv.y - bf2f(h1)),
                           (short)f2bf(kv.z - bf2f(h2)), (short)f2bf(kv.w - bf2f(h3)) };
            *(short4v*)&s_kh[row * 72 + c4 * 4] = hh;
            *(short4v*)&s_kl[row * 72 + c4 * 4] = ll;
        }
        __syncthreads();

        const int mrow = (w * 16 + l15) * 72;       // B-frag: n = lane&15 -> m col, k-contig
        const short8 bh0 = *(const short8*)&s_kh[mrow + quad * 8];
        const short8 bh1 = *(const short8*)&s_kh[mrow + 32 + quad * 8];
        const short8 bl0 = *(const short8*)&s_kl[mrow + quad * 8];
        const short8 bl1 = *(const short8*)&s_kl[mrow + 32 + quad * 8];
        f32x4 acc = {0.f, 0.f, 0.f, 0.f};
        acc = __builtin_amdgcn_mfma_f32_16x16x32_bf16(qh0, bh0, acc, 0, 0, 0);
        acc = __builtin_amdgcn_mfma_f32_16x16x32_bf16(qh1, bh1, acc, 0, 0, 0);
        acc = __builtin_amdgcn_mfma_f32_16x16x32_bf16(ql0, bh0, acc, 0, 0, 0);
        acc = __builtin_amdgcn_mfma_f32_16x16x32_bf16(ql1, bh1, acc, 0, 0, 0);
        acc = __builtin_amdgcn_mfma_f32_16x16x32_bf16(qh0, bl0, acc, 0, 0, 0);
        acc = __builtin_amdgcn_mfma_f32_16x16x32_bf16(qh1, bl1, acc, 0, 0, 0);

        if (quad < 2) {                              // C/D: col=lane&15, row=quad*4+r; rows 0..7 valid
            const int mglob = m0 + w * 16 + l15;
            float ksv[4];
            #pragma unroll
            for (int s = 0; s < 4; ++s) ksv[s] = ksub[((size_t)b * SS + s) * MM + mglob];
            #pragma unroll
            for (int r = 0; r < 4; ++r) {
                const int n = quad * 4 + r;
                s_S[n * 1036 + mglob] = acc[r];
                #pragma unroll
                for (int s = 0; s < 4; ++s)
                    dn[s][r] += __expf(acc[r] * qsr[s][r] * ksv[s]);
            }
        }
        __syncthreads();
    }

    // ---- denom reduce: cols via shuffle, waves via LDS ----
    #pragma unroll
    for (int s = 0; s < 4; ++s)
        #pragma unroll
        for (int r = 0; r < 4; ++r) {
            float v = dn[s][r];
            v += __shfl_xor(v, 1); v += __shfl_xor(v, 2);
            v += __shfl_xor(v, 4); v += __shfl_xor(v, 8);
            if (l15 == 0 && quad < 2)
                s_red[(w * 8 + quad * 4 + r) * 4 + s] = v;
        }
    __syncthreads();
    if (t < 32) {
        const int s = t >> 3, n = t & 7;
        float d = 0.f;
        #pragma unroll
        for (int ww = 0; ww < 4; ++ww) d += s_red[(ww * 8 + n) * 4 + s];
        s_inv[s * 8 + n] = 1.0f / d;
    }
    __syncthreads();

    // ---- Phase C: exp + attn store + stash; AV via MFMA ----
    const float* vg = vws + (size_t)bh * MM * CC;
    const int sn = t >> 3, mg = t & 7;               // exp mapping: 32 sn-rows x 8 m-chunks
    const int sC = sn >> 3, nC = sn & 7;
    const float invC = s_inv[sn];
    const float qsC  = s_qs[sn];
    const float* ksC = ksub + ((size_t)b * SS + sC) * MM;
    float* attnC = out_attn + (((size_t)(bh * SS + sC)) * NN + n0 + nC) * MM;
    const int Mt = w >> 1, nsel = w & 1;             // AV wave tiles
    f32x4 av0 = {0.f, 0.f, 0.f, 0.f}, av1 = {0.f, 0.f, 0.f, 0.f};

    #pragma unroll 1
    for (int mt = 0; mt < 16; ++mt) {
        const int m0 = mt * 64;
        {   // stage v transposed: vT[c][m-local], bf16
            const int mp = t >> 3, c8 = t & 7;
            #pragma unroll
            for (int i = 0; i < 2; ++i) {
                const int c4 = c8 + 8 * i;
                const float4 v0 = *(const float4*)&vg[(size_t)(m0 + 2 * mp) * CC + c4 * 4];
                const float4 v1 = *(const float4*)&vg[(size_t)(m0 + 2 * mp + 1) * CC + c4 * 4];
                const float a0[4] = {v0.x, v0.y, v0.z, v0.w};
                const float a1[4] = {v1.x, v1.y, v1.z, v1.w};
                #pragma unroll
                for (int j = 0; j < 4; ++j) {
                    short2v p = { (short)f2bf(a0[j]), (short)f2bf(a1[j]) };
                    *(short2v*)&s_vT[(c4 * 4 + j) * 72 + 2 * mp] = p;
                }
            }
        }
        {   // exp + normalize: fp32 global store + bf16 stash
            const f32x4 S0 = *(const f32x4*)&s_S[nC * 1036 + m0 + mg * 8];
            const f32x4 S1 = *(const f32x4*)&s_S[nC * 1036 + m0 + mg * 8 + 4];
            const float4 k0 = *(const float4*)&ksC[m0 + mg * 8];
            const float4 k1 = *(const float4*)&ksC[m0 + mg * 8 + 4];
            float4 e0, e1;
            e0.x = __expf(S0[0] * qsC * k0.x) * invC;
            e0.y = __expf(S0[1] * qsC * k0.y) * invC;
            e0.z = __expf(S0[2] * qsC * k0.z) * invC;
            e0.w = __expf(S0[3] * qsC * k0.w) * invC;
            e1.x = __expf(S1[0] * qsC * k1.x) * invC;
            e1.y = __expf(S1[1] * qsC * k1.y) * invC;
            e1.z = __expf(S1[2] * qsC * k1.z) * invC;
            e1.w = __expf(S1[3] * qsC * k1.w) * invC;
            *(float4*)&attnC[m0 + mg * 8]     = e0;
            *(float4*)&attnC[m0 + mg * 8 + 4] = e1;
            short8 pk = { (short)f2bf(e0.x), (short)f2bf(e0.y), (short)f2bf(e0.z), (short)f2bf(e0.w),
                          (short)f2bf(e1.x), (short)f2bf(e1.y), (short)f2bf(e1.z), (short)f2bf(e1.w) };
            *(short8*)&s_at[sn * 72 + mg * 8] = pk;
        }
        __syncthreads();
        // AV: D[32 sn][64 c] over K=64 this tile; wave: M-tile Mt, N-tiles {nsel, nsel+2}
        #pragma unroll
        for (int Ks = 0; Ks < 2; ++Ks) {
            const short8 a = *(const short8*)&s_at[(Mt * 16 + l15) * 72 + Ks * 32 + quad * 8];
            const short8 b0 = *(const short8*)&s_vT[(nsel * 16 + l15) * 72 + Ks * 32 + quad * 8];
            const short8 b1 = *(const short8*)&s_vT[((nsel + 2) * 16 + l15) * 72 + Ks * 32 + quad * 8];
            av0 = __builtin_amdgcn_mfma_f32_16x16x32_bf16(a, b0, av0, 0, 0, 0);
            av1 = __builtin_amdgcn_mfma_f32_16x16x32_bf16(a, b1, av1, 0, 0, 0);
        }
        __syncthreads();
    }

    // ---- hidden store: lane holds rows Mt*16+quad*4+r, cols Nt*16+l15 ----
    #pragma unroll
    for (int r = 0; r < 4; ++r) {
        const int snr = Mt * 16 + quad * 4 + r;
        const int s = snr >> 3, n = snr & 7;
        float* orow = out_hidden + (((size_t)b * SS + s) * NN + n0 + n) * DMODEL + h * CC;
        orow[nsel * 16 + l15]       = av0[r];
        orow[(nsel + 2) * 16 + l15] = av1[r];
    }
}

extern "C" void kernel_launch(void* const* d_in, const int* in_sizes, int n_in,
                              void* d_out, int out_size, void* d_ws, size_t ws_size,
                              hipStream_t stream) {
    const float* xq   = (const float*)d_in[0];
    const float* xk   = (const float*)d_in[1];
    const float* xv   = (const float*)d_in[2];
    const float* qsub = (const float*)d_in[3];
    const float* ksub = (const float*)d_in[4];
    const float* Wq   = (const float*)d_in[5];
    const float* bq   = (const float*)d_in[6];
    const float* Wk   = (const float*)d_in[7];
    const float* bk   = (const float*)d_in[8];
    const float* Wv   = (const float*)d_in[9];
    const float* bv   = (const float*)d_in[10];

    float* ws = (float*)d_ws;                       // 12.6 MB: q,k,v in (b,h,n,c)
    const size_t one = (size_t)BB * HH * NN * CC;
    float* out_hidden = (float*)d_out;              // (B,S,N,512)
    float* out_attn   = out_hidden + (size_t)BB * SS * NN * DMODEL;  // (B,H,S,N,M)

    proj_kernel<<<dim3(8, 32, 3), 256, 0, stream>>>(xq, xk, xv, Wq, Wk, Wv, bq, bk, bv, ws);
    attn_kernel<<<dim3(2048), 256, 0, stream>>>(ws, ws + one, ws + 2 * one,
                                                qsub, ksub, out_hidden, out_attn);
}